// Round 7
// baseline (1112.057 us; speedup 1.0000x reference)
//
#include <hip/hip_runtime.h>

#define NN 40000      // nodes
#define NE 400000     // edges
#define IC 64         // in channels
#define HC 16         // hidden
#define NR 90         // relations
#define NB 30         // bases
#define NC 8          // classes
#define MAXB 40       // max 256-edge chunks per relation (E[bin]=4444, 5sigma<4800, 40*256=10240 safe)

// ---------------- weight collapse + transpose ----------------
// W1t[r][o][i] (16x64 per rel), W2t[r][o][i] (8x16 per rel), r1t[o][i] (16x64), r2t[o][i] (8x16)
__global__ void k_weights(const float* __restrict__ comp1, const float* __restrict__ basis1,
                          const float* __restrict__ comp2, const float* __restrict__ basis2,
                          const float* __restrict__ root1, const float* __restrict__ root2,
                          float* __restrict__ W1t, float* __restrict__ W2t,
                          float* __restrict__ r1t, float* __restrict__ r2t) {
    const int n1 = NR * IC * HC;          // 92160
    const int n2 = NR * HC * NC;          // 11520
    const int n3 = IC * HC;               // 1024
    const int n4 = HC * NC;               // 128
    int t = blockIdx.x * blockDim.x + threadIdx.x;
    if (t < n1) {
        int r = t / (IC * HC);
        int rem = t - r * (IC * HC);
        int o = rem >> 6;                 // /64
        int i = rem & 63;
        float acc = 0.f;
#pragma unroll
        for (int b = 0; b < NB; ++b)
            acc += comp1[r * NB + b] * basis1[b * (IC * HC) + i * HC + o];
        W1t[t] = acc;
    } else if (t < n1 + n2) {
        int t2 = t - n1;
        int r = t2 / (HC * NC);
        int rem = t2 - r * (HC * NC);
        int o = rem >> 4;                 // /16
        int i = rem & 15;
        float acc = 0.f;
#pragma unroll
        for (int b = 0; b < NB; ++b)
            acc += comp2[r * NB + b] * basis2[b * (HC * NC) + i * NC + o];
        W2t[t2] = acc;
    } else if (t < n1 + n2 + n3) {
        int t3 = t - n1 - n2;
        int o = t3 >> 6, i = t3 & 63;
        r1t[t3] = root1[i * HC + o];
    } else if (t < n1 + n2 + n3 + n4) {
        int t4 = t - n1 - n2 - n3;
        int o = t4 >> 4, i = t4 & 15;
        r2t[t4] = root2[i * NC + o];
    }
}

// ---------------- per-(dst,rel) counts + relation histogram ----------------
__global__ void k_count(const int* __restrict__ dst, const int* __restrict__ et,
                        int* __restrict__ cnt, int* __restrict__ hist) {
    __shared__ int lh[NR];
    int tid = threadIdx.x;
    for (int i = tid; i < NR; i += blockDim.x) lh[i] = 0;
    __syncthreads();
    int e = blockIdx.x * blockDim.x + tid;
    if (e < NE) {
        int r = et[e];
        atomicAdd(&cnt[dst[e] * NR + r], 1);
        atomicAdd(&lh[r], 1);
    }
    __syncthreads();
    for (int i = tid; i < NR; i += blockDim.x)
        if (lh[i]) atomicAdd(&hist[i], lh[i]);
}

// ---------------- exclusive scan over 90 bins (1 thread, trivial) ----------------
__global__ void k_scan(const int* __restrict__ hist, int* __restrict__ binStart,
                       int* __restrict__ binCursor) {
    if (blockIdx.x == 0 && threadIdx.x == 0) {
        int run = 0;
        for (int r = 0; r < NR; ++r) {
            binStart[r] = run;
            binCursor[r] = run;
            run += hist[r];
        }
        binStart[NR] = run;
    }
}

// ---------------- scatter into relation-sorted arrays (pre-gather src/dst/norm) ----------------
__global__ void k_scatter(const int* __restrict__ src, const int* __restrict__ dst,
                          const int* __restrict__ et, const int* __restrict__ cnt,
                          int* __restrict__ binCursor,
                          int* __restrict__ sSrc, int* __restrict__ sDst,
                          float* __restrict__ sNrm) {
    int e = blockIdx.x * blockDim.x + threadIdx.x;
    if (e >= NE) return;
    int r = et[e];
    int d = dst[e];
    int pos = atomicAdd(&binCursor[r], 1);
    sSrc[pos] = src[e];
    sDst[pos] = d;
    int c = cnt[d * NR + r];
    sNrm[pos] = 1.0f / (float)(c > 1 ? c : 1);
}

// ---------------- layer-1 messages, relation-blocked, W in LDS ----------------
__global__ void __launch_bounds__(256)
k_msg1(const int* __restrict__ binStart, const int* __restrict__ sSrc,
       const int* __restrict__ sDst, const float* __restrict__ sNrm,
       const float* __restrict__ x, const float* __restrict__ W1t,
       float* __restrict__ agg1) {
    int r = blockIdx.x;
    int base = binStart[r], end = binStart[r + 1];
    if (base + (int)blockIdx.y * 256 >= end) return;
    __shared__ float4 wsh[256];           // 16 rows x 16 float4 = W1t[r]
    wsh[threadIdx.x] = ((const float4*)(W1t + r * (IC * HC)))[threadIdx.x];
    __syncthreads();
    int pos = base + blockIdx.y * 256 + threadIdx.x;
    if (pos >= end) return;
    int s = sSrc[pos], d = sDst[pos];
    float nm = sNrm[pos];
    const float4* xr = (const float4*)(x + s * IC);
    float4 xv[16];
#pragma unroll
    for (int iv = 0; iv < 16; ++iv) xv[iv] = xr[iv];
#pragma unroll
    for (int o = 0; o < HC; ++o) {
        float acc = 0.f;
#pragma unroll
        for (int iv = 0; iv < 16; ++iv) {
            float4 w = wsh[o * 16 + iv];
            acc += xv[iv].x * w.x + xv[iv].y * w.y + xv[iv].z * w.z + xv[iv].w * w.w;
        }
        atomicAdd(&agg1[d * HC + o], acc * nm);
    }
}

// ---------------- layer-1 node update: h = relu(agg1 + x@root1 + bias1) ----------------
__global__ void k_node1(const float* __restrict__ x, const float* __restrict__ r1t,
                        const float* __restrict__ bias1, const float* __restrict__ agg1,
                        float* __restrict__ h) {
    int t = blockIdx.x * blockDim.x + threadIdx.x;
    if (t >= NN * HC) return;
    int n = t >> 4;
    int o = t & (HC - 1);
    const float4* xr = (const float4*)(x + n * IC);
    const float4* wr = (const float4*)(r1t + o * IC);
    float acc = agg1[t] + bias1[o];
#pragma unroll
    for (int iv = 0; iv < 16; ++iv) {
        float4 xv = xr[iv], w = wr[iv];
        acc += xv.x * w.x + xv.y * w.y + xv.z * w.z + xv.w * w.w;
    }
    h[t] = fmaxf(acc, 0.f);
}

// ---------------- layer-2 messages, relation-blocked, W in LDS ----------------
__global__ void __launch_bounds__(256)
k_msg2(const int* __restrict__ binStart, const int* __restrict__ sSrc,
       const int* __restrict__ sDst, const float* __restrict__ sNrm,
       const float* __restrict__ h, const float* __restrict__ W2t,
       float* __restrict__ agg2) {
    int r = blockIdx.x;
    int base = binStart[r], end = binStart[r + 1];
    if (base + (int)blockIdx.y * 256 >= end) return;
    __shared__ float4 wsh[32];            // 8 rows x 4 float4 = W2t[r]
    if (threadIdx.x < 32)
        wsh[threadIdx.x] = ((const float4*)(W2t + r * (HC * NC)))[threadIdx.x];
    __syncthreads();
    int pos = base + blockIdx.y * 256 + threadIdx.x;
    if (pos >= end) return;
    int s = sSrc[pos], d = sDst[pos];
    float nm = sNrm[pos];
    const float4* hr = (const float4*)(h + s * HC);
    float4 hv[4];
#pragma unroll
    for (int iv = 0; iv < 4; ++iv) hv[iv] = hr[iv];
#pragma unroll
    for (int o = 0; o < NC; ++o) {
        float acc = 0.f;
#pragma unroll
        for (int iv = 0; iv < 4; ++iv) {
            float4 w = wsh[o * 4 + iv];
            acc += hv[iv].x * w.x + hv[iv].y * w.y + hv[iv].z * w.z + hv[iv].w * w.w;
        }
        atomicAdd(&agg2[d * NC + o], acc * nm);
    }
}

// ---------------- layer-2 node update + log_softmax ----------------
__global__ void k_node2(const float* __restrict__ h, const float* __restrict__ r2t,
                        const float* __restrict__ bias2, const float* __restrict__ agg2,
                        float* __restrict__ out) {
    int n = blockIdx.x * blockDim.x + threadIdx.x;
    if (n >= NN) return;
    const float4* hr = (const float4*)(h + n * HC);
    float4 hv[4];
#pragma unroll
    for (int iv = 0; iv < 4; ++iv) hv[iv] = hr[iv];
    float v[NC];
#pragma unroll
    for (int o = 0; o < NC; ++o) {
        const float4* wr = (const float4*)(r2t + o * HC);
        float acc = agg2[n * NC + o] + bias2[o];
#pragma unroll
        for (int iv = 0; iv < 4; ++iv) {
            float4 w = wr[iv];
            acc += hv[iv].x * w.x + hv[iv].y * w.y + hv[iv].z * w.z + hv[iv].w * w.w;
        }
        v[o] = acc;
    }
    float m = v[0];
#pragma unroll
    for (int o = 1; o < NC; ++o) m = fmaxf(m, v[o]);
    float s = 0.f;
#pragma unroll
    for (int o = 0; o < NC; ++o) s += expf(v[o] - m);
    float lse = m + logf(s);
    float4 o0, o1;
    o0.x = v[0] - lse; o0.y = v[1] - lse; o0.z = v[2] - lse; o0.w = v[3] - lse;
    o1.x = v[4] - lse; o1.y = v[5] - lse; o1.z = v[6] - lse; o1.w = v[7] - lse;
    float4* op = (float4*)(out + n * NC);
    op[0] = o0; op[1] = o1;
}

extern "C" void kernel_launch(void* const* d_in, const int* in_sizes, int n_in,
                              void* d_out, int out_size, void* d_ws, size_t ws_size,
                              hipStream_t stream) {
    const float* x      = (const float*)d_in[0];
    const int*   eidx   = (const int*)d_in[1];     // [2, NE]
    const int*   etype  = (const int*)d_in[2];
    const float* comp1  = (const float*)d_in[3];
    const float* basis1 = (const float*)d_in[4];
    const float* root1  = (const float*)d_in[5];
    const float* bias1  = (const float*)d_in[6];
    const float* comp2  = (const float*)d_in[7];
    const float* basis2 = (const float*)d_in[8];
    const float* root2  = (const float*)d_in[9];
    const float* bias2  = (const float*)d_in[10];
    float* out = (float*)d_out;

    const int* src = eidx;
    const int* dst = eidx + NE;

    char* ws = (char*)d_ws;
    size_t off = 0;
    auto alloc = [&](size_t bytes) {
        char* p = ws + off;
        off = (off + bytes + 255) & ~(size_t)255;
        return p;
    };
    float* W1t  = (float*)alloc(NR * IC * HC * sizeof(float));   // 368640
    float* W2t  = (float*)alloc(NR * HC * NC * sizeof(float));   // 46080
    float* r1t  = (float*)alloc(IC * HC * sizeof(float));        // 4096
    float* r2t  = (float*)alloc(HC * NC * sizeof(float));        // 512
    int*   cnt  = (int*)  alloc((size_t)NN * NR * sizeof(int));  // 14.4 MB
    int*   hist = (int*)  alloc(NR * sizeof(int));
    int*   binStart  = (int*)alloc((NR + 1) * sizeof(int));
    int*   binCursor = (int*)alloc(NR * sizeof(int));
    int*   sSrc = (int*)  alloc(NE * sizeof(int));               // 1.6 MB
    int*   sDst = (int*)  alloc(NE * sizeof(int));               // 1.6 MB
    float* sNrm = (float*)alloc(NE * sizeof(float));             // 1.6 MB
    float* agg1 = (float*)alloc(NN * HC * sizeof(float));        // 2.56 MB
    float* h    = (float*)alloc(NN * HC * sizeof(float));        // 2.56 MB
    float* agg2 = (float*)alloc(NN * NC * sizeof(float));        // 1.28 MB

    hipMemsetAsync(cnt,  0, (size_t)NN * NR * sizeof(int), stream);
    hipMemsetAsync(hist, 0, NR * sizeof(int), stream);
    hipMemsetAsync(agg1, 0, NN * HC * sizeof(float), stream);
    hipMemsetAsync(agg2, 0, NN * NC * sizeof(float), stream);

    const int B = 256;
    int nW = NR * IC * HC + NR * HC * NC + IC * HC + HC * NC;
    k_weights<<<(nW + B - 1) / B, B, 0, stream>>>(comp1, basis1, comp2, basis2,
                                                  root1, root2, W1t, W2t, r1t, r2t);
    k_count  <<<(NE + B - 1) / B, B, 0, stream>>>(dst, etype, cnt, hist);
    k_scan   <<<1, 64, 0, stream>>>(hist, binStart, binCursor);
    k_scatter<<<(NE + B - 1) / B, B, 0, stream>>>(src, dst, etype, cnt, binCursor,
                                                  sSrc, sDst, sNrm);
    k_msg1   <<<dim3(NR, MAXB), B, 0, stream>>>(binStart, sSrc, sDst, sNrm, x, W1t, agg1);
    k_node1  <<<(NN * HC + B - 1) / B, B, 0, stream>>>(x, r1t, bias1, agg1, h);
    k_msg2   <<<dim3(NR, MAXB), B, 0, stream>>>(binStart, sSrc, sDst, sNrm, h, W2t, agg2);
    k_node2  <<<(NN + B - 1) / B, B, 0, stream>>>(h, r2t, bias2, agg2, out);
}

// Round 8
// 714.119 us; speedup vs baseline: 1.5572x; 1.5572x over previous
//
#include <hip/hip_runtime.h>

#define NN 40000      // nodes
#define NE 400000     // edges
#define IC 64         // in channels
#define HC 16         // hidden
#define NR 90         // relations
#define NB 30         // bases
#define NC 8          // classes
#define MAXB 40       // max 256-edge chunks per relation (E[bin]=4444, 5sigma<4800, 40*256=10240 safe)

// ---------------- weight collapse + transpose ----------------
// W1t[r][o][i] (16x64 per rel), W2t[r][o][i] (8x16 per rel), r1t[o][i] (16x64), r2t[o][i] (8x16)
__global__ void k_weights(const float* __restrict__ comp1, const float* __restrict__ basis1,
                          const float* __restrict__ comp2, const float* __restrict__ basis2,
                          const float* __restrict__ root1, const float* __restrict__ root2,
                          float* __restrict__ W1t, float* __restrict__ W2t,
                          float* __restrict__ r1t, float* __restrict__ r2t) {
    const int n1 = NR * IC * HC;          // 92160
    const int n2 = NR * HC * NC;          // 11520
    const int n3 = IC * HC;               // 1024
    const int n4 = HC * NC;               // 128
    int t = blockIdx.x * blockDim.x + threadIdx.x;
    if (t < n1) {
        int r = t / (IC * HC);
        int rem = t - r * (IC * HC);
        int o = rem >> 6;                 // /64
        int i = rem & 63;
        float acc = 0.f;
#pragma unroll
        for (int b = 0; b < NB; ++b)
            acc += comp1[r * NB + b] * basis1[b * (IC * HC) + i * HC + o];
        W1t[t] = acc;
    } else if (t < n1 + n2) {
        int t2 = t - n1;
        int r = t2 / (HC * NC);
        int rem = t2 - r * (HC * NC);
        int o = rem >> 4;                 // /16
        int i = rem & 15;
        float acc = 0.f;
#pragma unroll
        for (int b = 0; b < NB; ++b)
            acc += comp2[r * NB + b] * basis2[b * (HC * NC) + i * NC + o];
        W2t[t2] = acc;
    } else if (t < n1 + n2 + n3) {
        int t3 = t - n1 - n2;
        int o = t3 >> 6, i = t3 & 63;
        r1t[t3] = root1[i * HC + o];
    } else if (t < n1 + n2 + n3 + n4) {
        int t4 = t - n1 - n2 - n3;
        int o = t4 >> 4, i = t4 & 15;
        r2t[t4] = root2[i * NC + o];
    }
}

// ---------------- per-(dst,rel) counts + relation histogram ----------------
__global__ void k_count(const int* __restrict__ dst, const int* __restrict__ et,
                        int* __restrict__ cnt, int* __restrict__ hist) {
    __shared__ int lh[NR];
    int tid = threadIdx.x;
    for (int i = tid; i < NR; i += blockDim.x) lh[i] = 0;
    __syncthreads();
    int e = blockIdx.x * blockDim.x + tid;
    if (e < NE) {
        int r = et[e];
        atomicAdd(&cnt[dst[e] * NR + r], 1);
        atomicAdd(&lh[r], 1);
    }
    __syncthreads();
    for (int i = tid; i < NR; i += blockDim.x)
        if (lh[i]) atomicAdd(&hist[i], lh[i]);
}

// ---------------- exclusive scan over 90 bins (1 thread, trivial) ----------------
__global__ void k_scan(const int* __restrict__ hist, int* __restrict__ binStart,
                       int* __restrict__ binCursor) {
    if (blockIdx.x == 0 && threadIdx.x == 0) {
        int run = 0;
        for (int r = 0; r < NR; ++r) {
            binStart[r] = run;
            binCursor[r] = run;
            run += hist[r];
        }
        binStart[NR] = run;
    }
}

// ---------------- two-level scatter: LDS rank + one global atomic per (rel, block) ----------------
__global__ void __launch_bounds__(256)
k_scatter(const int* __restrict__ src, const int* __restrict__ dst,
          const int* __restrict__ et, const int* __restrict__ cnt,
          int* __restrict__ binCursor,
          int* __restrict__ sSrc, int* __restrict__ sDst,
          float* __restrict__ sNrm) {
    __shared__ int lhist[NR];   // per-block histogram (then reused as nothing else)
    __shared__ int lbase[NR];   // global base of this block's chunk per relation
    int tid = threadIdx.x;
    for (int i = tid; i < NR; i += blockDim.x) lhist[i] = 0;
    __syncthreads();
    int e = blockIdx.x * blockDim.x + tid;
    int r = 0, d = 0, s = 0, myrank = 0;
    bool active = (e < NE);
    if (active) {
        r = et[e];
        d = dst[e];
        s = src[e];
        myrank = atomicAdd(&lhist[r], 1);      // LDS atomic with return = in-block rank
    }
    __syncthreads();
    for (int i = tid; i < NR; i += blockDim.x) {
        int c = lhist[i];
        lbase[i] = c ? atomicAdd(&binCursor[i], c) : 0;  // one global atomic per rel per block
    }
    __syncthreads();
    if (active) {
        int pos = lbase[r] + myrank;
        sSrc[pos] = s;
        sDst[pos] = d;
        int c = cnt[d * NR + r];
        sNrm[pos] = 1.0f / (float)(c > 1 ? c : 1);
    }
}

// ---------------- layer-1 messages, relation-blocked, W in LDS ----------------
__global__ void __launch_bounds__(256)
k_msg1(const int* __restrict__ binStart, const int* __restrict__ sSrc,
       const int* __restrict__ sDst, const float* __restrict__ sNrm,
       const float* __restrict__ x, const float* __restrict__ W1t,
       float* __restrict__ agg1) {
    int r = blockIdx.x;
    int base = binStart[r], end = binStart[r + 1];
    if (base + (int)blockIdx.y * 256 >= end) return;
    __shared__ float4 wsh[256];           // 16 rows x 16 float4 = W1t[r]
    wsh[threadIdx.x] = ((const float4*)(W1t + r * (IC * HC)))[threadIdx.x];
    __syncthreads();
    int pos = base + blockIdx.y * 256 + threadIdx.x;
    if (pos >= end) return;
    int s = sSrc[pos], d = sDst[pos];
    float nm = sNrm[pos];
    const float4* xr = (const float4*)(x + s * IC);
    float4 xv[16];
#pragma unroll
    for (int iv = 0; iv < 16; ++iv) xv[iv] = xr[iv];
#pragma unroll
    for (int o = 0; o < HC; ++o) {
        float acc = 0.f;
#pragma unroll
        for (int iv = 0; iv < 16; ++iv) {
            float4 w = wsh[o * 16 + iv];
            acc += xv[iv].x * w.x + xv[iv].y * w.y + xv[iv].z * w.z + xv[iv].w * w.w;
        }
        atomicAdd(&agg1[d * HC + o], acc * nm);
    }
}

// ---------------- layer-1 node update: h = relu(agg1 + x@root1 + bias1) ----------------
__global__ void k_node1(const float* __restrict__ x, const float* __restrict__ r1t,
                        const float* __restrict__ bias1, const float* __restrict__ agg1,
                        float* __restrict__ h) {
    int t = blockIdx.x * blockDim.x + threadIdx.x;
    if (t >= NN * HC) return;
    int n = t >> 4;
    int o = t & (HC - 1);
    const float4* xr = (const float4*)(x + n * IC);
    const float4* wr = (const float4*)(r1t + o * IC);
    float acc = agg1[t] + bias1[o];
#pragma unroll
    for (int iv = 0; iv < 16; ++iv) {
        float4 xv = xr[iv], w = wr[iv];
        acc += xv.x * w.x + xv.y * w.y + xv.z * w.z + xv.w * w.w;
    }
    h[t] = fmaxf(acc, 0.f);
}

// ---------------- layer-2 messages, relation-blocked, W in LDS ----------------
__global__ void __launch_bounds__(256)
k_msg2(const int* __restrict__ binStart, const int* __restrict__ sSrc,
       const int* __restrict__ sDst, const float* __restrict__ sNrm,
       const float* __restrict__ h, const float* __restrict__ W2t,
       float* __restrict__ agg2) {
    int r = blockIdx.x;
    int base = binStart[r], end = binStart[r + 1];
    if (base + (int)blockIdx.y * 256 >= end) return;
    __shared__ float4 wsh[32];            // 8 rows x 4 float4 = W2t[r]
    if (threadIdx.x < 32)
        wsh[threadIdx.x] = ((const float4*)(W2t + r * (HC * NC)))[threadIdx.x];
    __syncthreads();
    int pos = base + blockIdx.y * 256 + threadIdx.x;
    if (pos >= end) return;
    int s = sSrc[pos], d = sDst[pos];
    float nm = sNrm[pos];
    const float4* hr = (const float4*)(h + s * HC);
    float4 hv[4];
#pragma unroll
    for (int iv = 0; iv < 4; ++iv) hv[iv] = hr[iv];
#pragma unroll
    for (int o = 0; o < NC; ++o) {
        float acc = 0.f;
#pragma unroll
        for (int iv = 0; iv < 4; ++iv) {
            float4 w = wsh[o * 4 + iv];
            acc += hv[iv].x * w.x + hv[iv].y * w.y + hv[iv].z * w.z + hv[iv].w * w.w;
        }
        atomicAdd(&agg2[d * NC + o], acc * nm);
    }
}

// ---------------- layer-2 node update + log_softmax ----------------
__global__ void k_node2(const float* __restrict__ h, const float* __restrict__ r2t,
                        const float* __restrict__ bias2, const float* __restrict__ agg2,
                        float* __restrict__ out) {
    int n = blockIdx.x * blockDim.x + threadIdx.x;
    if (n >= NN) return;
    const float4* hr = (const float4*)(h + n * HC);
    float4 hv[4];
#pragma unroll
    for (int iv = 0; iv < 4; ++iv) hv[iv] = hr[iv];
    float v[NC];
#pragma unroll
    for (int o = 0; o < NC; ++o) {
        const float4* wr = (const float4*)(r2t + o * HC);
        float acc = agg2[n * NC + o] + bias2[o];
#pragma unroll
        for (int iv = 0; iv < 4; ++iv) {
            float4 w = wr[iv];
            acc += hv[iv].x * w.x + hv[iv].y * w.y + hv[iv].z * w.z + hv[iv].w * w.w;
        }
        v[o] = acc;
    }
    float m = v[0];
#pragma unroll
    for (int o = 1; o < NC; ++o) m = fmaxf(m, v[o]);
    float s = 0.f;
#pragma unroll
    for (int o = 0; o < NC; ++o) s += expf(v[o] - m);
    float lse = m + logf(s);
    float4 o0, o1;
    o0.x = v[0] - lse; o0.y = v[1] - lse; o0.z = v[2] - lse; o0.w = v[3] - lse;
    o1.x = v[4] - lse; o1.y = v[5] - lse; o1.z = v[6] - lse; o1.w = v[7] - lse;
    float4* op = (float4*)(out + n * NC);
    op[0] = o0; op[1] = o1;
}

extern "C" void kernel_launch(void* const* d_in, const int* in_sizes, int n_in,
                              void* d_out, int out_size, void* d_ws, size_t ws_size,
                              hipStream_t stream) {
    const float* x      = (const float*)d_in[0];
    const int*   eidx   = (const int*)d_in[1];     // [2, NE]
    const int*   etype  = (const int*)d_in[2];
    const float* comp1  = (const float*)d_in[3];
    const float* basis1 = (const float*)d_in[4];
    const float* root1  = (const float*)d_in[5];
    const float* bias1  = (const float*)d_in[6];
    const float* comp2  = (const float*)d_in[7];
    const float* basis2 = (const float*)d_in[8];
    const float* root2  = (const float*)d_in[9];
    const float* bias2  = (const float*)d_in[10];
    float* out = (float*)d_out;

    const int* src = eidx;
    const int* dst = eidx + NE;

    char* ws = (char*)d_ws;
    size_t off = 0;
    auto alloc = [&](size_t bytes) {
        char* p = ws + off;
        off = (off + bytes + 255) & ~(size_t)255;
        return p;
    };
    float* W1t  = (float*)alloc(NR * IC * HC * sizeof(float));   // 368640
    float* W2t  = (float*)alloc(NR * HC * NC * sizeof(float));   // 46080
    float* r1t  = (float*)alloc(IC * HC * sizeof(float));        // 4096
    float* r2t  = (float*)alloc(HC * NC * sizeof(float));        // 512
    int*   cnt  = (int*)  alloc((size_t)NN * NR * sizeof(int));  // 14.4 MB
    int*   hist = (int*)  alloc(NR * sizeof(int));
    int*   binStart  = (int*)alloc((NR + 1) * sizeof(int));
    int*   binCursor = (int*)alloc(NR * sizeof(int));
    int*   sSrc = (int*)  alloc(NE * sizeof(int));               // 1.6 MB
    int*   sDst = (int*)  alloc(NE * sizeof(int));               // 1.6 MB
    float* sNrm = (float*)alloc(NE * sizeof(float));             // 1.6 MB
    float* agg1 = (float*)alloc(NN * HC * sizeof(float));        // 2.56 MB
    float* h    = (float*)alloc(NN * HC * sizeof(float));        // 2.56 MB
    float* agg2 = (float*)alloc(NN * NC * sizeof(float));        // 1.28 MB

    hipMemsetAsync(cnt,  0, (size_t)NN * NR * sizeof(int), stream);
    hipMemsetAsync(hist, 0, NR * sizeof(int), stream);
    hipMemsetAsync(agg1, 0, NN * HC * sizeof(float), stream);
    hipMemsetAsync(agg2, 0, NN * NC * sizeof(float), stream);

    const int B = 256;
    int nW = NR * IC * HC + NR * HC * NC + IC * HC + HC * NC;
    k_weights<<<(nW + B - 1) / B, B, 0, stream>>>(comp1, basis1, comp2, basis2,
                                                  root1, root2, W1t, W2t, r1t, r2t);
    k_count  <<<(NE + B - 1) / B, B, 0, stream>>>(dst, etype, cnt, hist);
    k_scan   <<<1, 64, 0, stream>>>(hist, binStart, binCursor);
    k_scatter<<<(NE + B - 1) / B, B, 0, stream>>>(src, dst, etype, cnt, binCursor,
                                                  sSrc, sDst, sNrm);
    k_msg1   <<<dim3(NR, MAXB), B, 0, stream>>>(binStart, sSrc, sDst, sNrm, x, W1t, agg1);
    k_node1  <<<(NN * HC + B - 1) / B, B, 0, stream>>>(x, r1t, bias1, agg1, h);
    k_msg2   <<<dim3(NR, MAXB), B, 0, stream>>>(binStart, sSrc, sDst, sNrm, h, W2t, agg2);
    k_node2  <<<(NN + B - 1) / B, B, 0, stream>>>(h, r2t, bias2, agg2, out);
}

// Round 9
// 292.953 us; speedup vs baseline: 3.7960x; 2.4377x over previous
//
#include <hip/hip_runtime.h>

#define NN 40000      // nodes
#define NE 400000     // edges
#define IC 64         // in channels
#define HC 16         // hidden
#define NR 90         // relations
#define NB 30         // bases
#define NC 8          // classes
#define EPB1 16       // edges per block, msg1 (16 edges x 16 outs = 256 thr)
#define EPB2 32       // edges per block, msg2 (32 edges x 8 outs = 256 thr)
#define CH1 320       // chunks per relation, msg1: 320*16 = 5120 cap (bin mean 4444, sd 66)
#define CH2 160       // chunks per relation, msg2: 160*32 = 5120 cap

// ---------------- weight collapse + transpose ----------------
// W1t[r][o][i] (16x64 per rel), W2t[r][o][i] (8x16 per rel), r1t[o][i], r2t[o][i]
__global__ void k_weights(const float* __restrict__ comp1, const float* __restrict__ basis1,
                          const float* __restrict__ comp2, const float* __restrict__ basis2,
                          const float* __restrict__ root1, const float* __restrict__ root2,
                          float* __restrict__ W1t, float* __restrict__ W2t,
                          float* __restrict__ r1t, float* __restrict__ r2t) {
    const int n1 = NR * IC * HC;          // 92160
    const int n2 = NR * HC * NC;          // 11520
    const int n3 = IC * HC;               // 1024
    const int n4 = HC * NC;               // 128
    int t = blockIdx.x * blockDim.x + threadIdx.x;
    if (t < n1) {
        int r = t / (IC * HC);
        int rem = t - r * (IC * HC);
        int o = rem >> 6;                 // /64
        int i = rem & 63;
        float acc = 0.f;
#pragma unroll
        for (int b = 0; b < NB; ++b)
            acc += comp1[r * NB + b] * basis1[b * (IC * HC) + i * HC + o];
        W1t[t] = acc;
    } else if (t < n1 + n2) {
        int t2 = t - n1;
        int r = t2 / (HC * NC);
        int rem = t2 - r * (HC * NC);
        int o = rem >> 4;                 // /16
        int i = rem & 15;
        float acc = 0.f;
#pragma unroll
        for (int b = 0; b < NB; ++b)
            acc += comp2[r * NB + b] * basis2[b * (HC * NC) + i * NC + o];
        W2t[t2] = acc;
    } else if (t < n1 + n2 + n3) {
        int t3 = t - n1 - n2;
        int o = t3 >> 6, i = t3 & 63;
        r1t[t3] = root1[i * HC + o];
    } else if (t < n1 + n2 + n3 + n4) {
        int t4 = t - n1 - n2 - n3;
        int o = t4 >> 4, i = t4 & 15;
        r2t[t4] = root2[i * NC + o];
    }
}

// ---------------- per-(dst,rel) counts + relation histogram ----------------
__global__ void k_count(const int* __restrict__ dst, const int* __restrict__ et,
                        int* __restrict__ cnt, int* __restrict__ hist) {
    __shared__ int lh[NR];
    int tid = threadIdx.x;
    for (int i = tid; i < NR; i += blockDim.x) lh[i] = 0;
    __syncthreads();
    int e = blockIdx.x * blockDim.x + tid;
    if (e < NE) {
        int r = et[e];
        atomicAdd(&cnt[dst[e] * NR + r], 1);
        atomicAdd(&lh[r], 1);
    }
    __syncthreads();
    for (int i = tid; i < NR; i += blockDim.x)
        if (lh[i]) atomicAdd(&hist[i], lh[i]);
}

// ---------------- exclusive scan over 90 bins (1 thread, trivial) ----------------
__global__ void k_scan(const int* __restrict__ hist, int* __restrict__ binStart,
                       int* __restrict__ binCursor) {
    if (blockIdx.x == 0 && threadIdx.x == 0) {
        int run = 0;
        for (int r = 0; r < NR; ++r) {
            binStart[r] = run;
            binCursor[r] = run;
            run += hist[r];
        }
        binStart[NR] = run;
    }
}

// ---------------- two-level scatter: LDS rank + one global atomic per (rel, block) ----------------
__global__ void __launch_bounds__(256)
k_scatter(const int* __restrict__ src, const int* __restrict__ dst,
          const int* __restrict__ et, const int* __restrict__ cnt,
          int* __restrict__ binCursor,
          int* __restrict__ sSrc, int* __restrict__ sDst,
          float* __restrict__ sNrm) {
    __shared__ int lhist[NR];
    __shared__ int lbase[NR];
    int tid = threadIdx.x;
    for (int i = tid; i < NR; i += blockDim.x) lhist[i] = 0;
    __syncthreads();
    int e = blockIdx.x * blockDim.x + tid;
    int r = 0, d = 0, s = 0, myrank = 0;
    bool active = (e < NE);
    if (active) {
        r = et[e];
        d = dst[e];
        s = src[e];
        myrank = atomicAdd(&lhist[r], 1);      // LDS atomic = in-block rank
    }
    __syncthreads();
    for (int i = tid; i < NR; i += blockDim.x) {
        int c = lhist[i];
        lbase[i] = c ? atomicAdd(&binCursor[i], c) : 0;  // one global atomic per rel per block
    }
    __syncthreads();
    if (active) {
        int pos = lbase[r] + myrank;
        if (pos < NE) {                        // clamp: protects rocprof kernel-replay (stale cursors)
            sSrc[pos] = s;
            sDst[pos] = d;
            int c = cnt[d * NR + r];
            sNrm[pos] = 1.0f / (float)(c > 1 ? c : 1);
        }
    }
}

// ---------------- layer-1 messages: 16 edges x 16 outs per block, W in padded LDS ----------------
__global__ void __launch_bounds__(256)
k_msg1(const int* __restrict__ binStart, const int* __restrict__ sSrc,
       const int* __restrict__ sDst, const float* __restrict__ sNrm,
       const float* __restrict__ x, const float* __restrict__ W1t,
       float* __restrict__ agg1) {
    int r = blockIdx.x;
    int base = binStart[r], end = binStart[r + 1];
    int chunk0 = base + (int)blockIdx.y * EPB1;
    if (chunk0 >= end) return;
    __shared__ float wsh[16 * 68];        // [o][68]: pad 68 -> 2-way-max bank aliasing (free)
    {
        int t = threadIdx.x;              // 256 float4 = full 16x64 tile
        float4 v = ((const float4*)(W1t + r * (IC * HC)))[t];
        int o = t >> 4, i4 = t & 15;
        float* dp = &wsh[o * 68 + 4 * i4];
        dp[0] = v.x; dp[1] = v.y; dp[2] = v.z; dp[3] = v.w;
    }
    __syncthreads();
    int el = threadIdx.x >> 4;            // local edge 0..15
    int o  = threadIdx.x & 15;            // output channel
    int pos = chunk0 + el;
    if (pos >= end) return;
    int s = sSrc[pos], d = sDst[pos];
    float nm = sNrm[pos];
    const float4* xr = (const float4*)(x + s * IC);
    float acc = 0.f;
#pragma unroll
    for (int iv = 0; iv < 16; ++iv) {
        float4 xv = xr[iv];                                   // broadcast across 16 lanes
        float4 w = *(const float4*)&wsh[o * 68 + 4 * iv];     // conflict-free
        acc += xv.x * w.x + xv.y * w.y + xv.z * w.z + xv.w * w.w;
    }
    atomicAdd(&agg1[d * HC + o], acc * nm);   // 16 consecutive lanes -> 1 cache line
}

// ---------------- layer-1 node update: h = relu(agg1 + x@root1 + bias1) ----------------
__global__ void k_node1(const float* __restrict__ x, const float* __restrict__ r1t,
                        const float* __restrict__ bias1, const float* __restrict__ agg1,
                        float* __restrict__ h) {
    int t = blockIdx.x * blockDim.x + threadIdx.x;
    if (t >= NN * HC) return;
    int n = t >> 4;
    int o = t & (HC - 1);
    const float4* xr = (const float4*)(x + n * IC);
    const float4* wr = (const float4*)(r1t + o * IC);
    float acc = agg1[t] + bias1[o];
#pragma unroll
    for (int iv = 0; iv < 16; ++iv) {
        float4 xv = xr[iv], w = wr[iv];
        acc += xv.x * w.x + xv.y * w.y + xv.z * w.z + xv.w * w.w;
    }
    h[t] = fmaxf(acc, 0.f);
}

// ---------------- layer-2 messages: 32 edges x 8 outs per block, W in padded LDS ----------------
__global__ void __launch_bounds__(256)
k_msg2(const int* __restrict__ binStart, const int* __restrict__ sSrc,
       const int* __restrict__ sDst, const float* __restrict__ sNrm,
       const float* __restrict__ h, const float* __restrict__ W2t,
       float* __restrict__ agg2) {
    int r = blockIdx.x;
    int base = binStart[r], end = binStart[r + 1];
    int chunk0 = base + (int)blockIdx.y * EPB2;
    if (chunk0 >= end) return;
    __shared__ float wsh[8 * 20];         // [o][20]: 8 disjoint 4-bank spans, conflict-free
    if (threadIdx.x < 32) {
        float4 v = ((const float4*)(W2t + r * (HC * NC)))[threadIdx.x];
        int o = threadIdx.x >> 2, i4 = threadIdx.x & 3;
        float* dp = &wsh[o * 20 + 4 * i4];
        dp[0] = v.x; dp[1] = v.y; dp[2] = v.z; dp[3] = v.w;
    }
    __syncthreads();
    int el = threadIdx.x >> 3;            // local edge 0..31
    int o  = threadIdx.x & 7;
    int pos = chunk0 + el;
    if (pos >= end) return;
    int s = sSrc[pos], d = sDst[pos];
    float nm = sNrm[pos];
    const float4* hr = (const float4*)(h + s * HC);
    float acc = 0.f;
#pragma unroll
    for (int iv = 0; iv < 4; ++iv) {
        float4 hv = hr[iv];                                   // broadcast across 8 lanes
        float4 w = *(const float4*)&wsh[o * 20 + 4 * iv];
        acc += hv.x * w.x + hv.y * w.y + hv.z * w.z + hv.w * w.w;
    }
    atomicAdd(&agg2[d * NC + o], acc * nm);   // 8 consecutive lanes -> 1 cache line
}

// ---------------- layer-2 node update + log_softmax ----------------
__global__ void k_node2(const float* __restrict__ h, const float* __restrict__ r2t,
                        const float* __restrict__ bias2, const float* __restrict__ agg2,
                        float* __restrict__ out) {
    int n = blockIdx.x * blockDim.x + threadIdx.x;
    if (n >= NN) return;
    const float4* hr = (const float4*)(h + n * HC);
    float4 hv[4];
#pragma unroll
    for (int iv = 0; iv < 4; ++iv) hv[iv] = hr[iv];
    float v[NC];
#pragma unroll
    for (int o = 0; o < NC; ++o) {
        const float4* wr = (const float4*)(r2t + o * HC);
        float acc = agg2[n * NC + o] + bias2[o];
#pragma unroll
        for (int iv = 0; iv < 4; ++iv) {
            float4 w = wr[iv];
            acc += hv[iv].x * w.x + hv[iv].y * w.y + hv[iv].z * w.z + hv[iv].w * w.w;
        }
        v[o] = acc;
    }
    float m = v[0];
#pragma unroll
    for (int o = 1; o < NC; ++o) m = fmaxf(m, v[o]);
    float s = 0.f;
#pragma unroll
    for (int o = 0; o < NC; ++o) s += expf(v[o] - m);
    float lse = m + logf(s);
    float4 o0, o1;
    o0.x = v[0] - lse; o0.y = v[1] - lse; o0.z = v[2] - lse; o0.w = v[3] - lse;
    o1.x = v[4] - lse; o1.y = v[5] - lse; o1.z = v[6] - lse; o1.w = v[7] - lse;
    float4* op = (float4*)(out + n * NC);
    op[0] = o0; op[1] = o1;
}

extern "C" void kernel_launch(void* const* d_in, const int* in_sizes, int n_in,
                              void* d_out, int out_size, void* d_ws, size_t ws_size,
                              hipStream_t stream) {
    const float* x      = (const float*)d_in[0];
    const int*   eidx   = (const int*)d_in[1];     // [2, NE]
    const int*   etype  = (const int*)d_in[2];
    const float* comp1  = (const float*)d_in[3];
    const float* basis1 = (const float*)d_in[4];
    const float* root1  = (const float*)d_in[5];
    const float* bias1  = (const float*)d_in[6];
    const float* comp2  = (const float*)d_in[7];
    const float* basis2 = (const float*)d_in[8];
    const float* root2  = (const float*)d_in[9];
    const float* bias2  = (const float*)d_in[10];
    float* out = (float*)d_out;

    const int* src = eidx;
    const int* dst = eidx + NE;

    char* ws = (char*)d_ws;
    size_t off = 0;
    auto alloc = [&](size_t bytes) {
        char* p = ws + off;
        off = (off + bytes + 255) & ~(size_t)255;
        return p;
    };
    float* W1t  = (float*)alloc(NR * IC * HC * sizeof(float));   // 368640
    float* W2t  = (float*)alloc(NR * HC * NC * sizeof(float));   // 46080
    float* r1t  = (float*)alloc(IC * HC * sizeof(float));        // 4096
    float* r2t  = (float*)alloc(HC * NC * sizeof(float));        // 512
    int*   cnt  = (int*)  alloc((size_t)NN * NR * sizeof(int));  // 14.4 MB
    int*   hist = (int*)  alloc(NR * sizeof(int));
    int*   binStart  = (int*)alloc((NR + 1) * sizeof(int));
    int*   binCursor = (int*)alloc(NR * sizeof(int));
    int*   sSrc = (int*)  alloc(NE * sizeof(int));               // 1.6 MB
    int*   sDst = (int*)  alloc(NE * sizeof(int));               // 1.6 MB
    float* sNrm = (float*)alloc(NE * sizeof(float));             // 1.6 MB
    float* agg1 = (float*)alloc(NN * HC * sizeof(float));        // 2.56 MB
    float* h    = (float*)alloc(NN * HC * sizeof(float));        // 2.56 MB
    float* agg2 = (float*)alloc(NN * NC * sizeof(float));        // 1.28 MB

    hipMemsetAsync(cnt,  0, (size_t)NN * NR * sizeof(int), stream);
    hipMemsetAsync(hist, 0, NR * sizeof(int), stream);
    hipMemsetAsync(agg1, 0, NN * HC * sizeof(float), stream);
    hipMemsetAsync(agg2, 0, NN * NC * sizeof(float), stream);

    const int B = 256;
    int nW = NR * IC * HC + NR * HC * NC + IC * HC + HC * NC;
    k_weights<<<(nW + B - 1) / B, B, 0, stream>>>(comp1, basis1, comp2, basis2,
                                                  root1, root2, W1t, W2t, r1t, r2t);
    k_count  <<<(NE + B - 1) / B, B, 0, stream>>>(dst, etype, cnt, hist);
    k_scan   <<<1, 64, 0, stream>>>(hist, binStart, binCursor);
    k_scatter<<<(NE + B - 1) / B, B, 0, stream>>>(src, dst, etype, cnt, binCursor,
                                                  sSrc, sDst, sNrm);
    k_msg1   <<<dim3(NR, CH1), B, 0, stream>>>(binStart, sSrc, sDst, sNrm, x, W1t, agg1);
    k_node1  <<<(NN * HC + B - 1) / B, B, 0, stream>>>(x, r1t, bias1, agg1, h);
    k_msg2   <<<dim3(NR, CH2), B, 0, stream>>>(binStart, sSrc, sDst, sNrm, h, W2t, agg2);
    k_node2  <<<(NN + B - 1) / B, B, 0, stream>>>(h, r2t, bias2, agg2, out);
}

// Round 11
// 280.712 us; speedup vs baseline: 3.9616x; 1.0436x over previous
//
#include <hip/hip_runtime.h>

#define NN 40000      // nodes
#define NE 400000     // edges
#define IC 64         // in channels
#define HC 16         // hidden
#define NR 90         // relations
#define NB 30         // bases
#define NC 8          // classes
#define EPB1 16       // edges per block, msg1 (16 edges x 16 outs = 256 thr)
#define EPB2 32       // edges per block, msg2 (32 edges x 8 outs = 256 thr)
#define CH1 320       // chunks per relation, msg1: 320*16 = 5120 cap (bin mean 4444, sd 66)
#define CH2 160       // chunks per relation, msg2: 160*32 = 5120 cap

// ---------------- fused: weight collapse/transpose + (dst,rel) counts + rel histogram ----------------
#define NW (NR*IC*HC + NR*HC*NC + IC*HC + HC*NC)   // 104832
#define WBLK ((NW + 255) / 256)                    // 410 weight blocks

__global__ void __launch_bounds__(256)
k_wc(const float* __restrict__ comp1, const float* __restrict__ basis1,
     const float* __restrict__ comp2, const float* __restrict__ basis2,
     const float* __restrict__ root1, const float* __restrict__ root2,
     float* __restrict__ W1t, float* __restrict__ W2t,
     float* __restrict__ r1t, float* __restrict__ r2t,
     const int* __restrict__ dst, const int* __restrict__ et,
     int* __restrict__ cnt, int* __restrict__ hist) {
    __shared__ int lh[NR];
    int b = blockIdx.x;
    if (b < WBLK) {
        const int n1 = NR * IC * HC;          // 92160
        const int n2 = NR * HC * NC;          // 11520
        const int n3 = IC * HC;               // 1024
        const int n4 = HC * NC;               // 128
        int t = b * 256 + threadIdx.x;
        if (t < n1) {
            int r = t / (IC * HC);
            int rem = t - r * (IC * HC);
            int o = rem >> 6, i = rem & 63;
            float acc = 0.f;
#pragma unroll
            for (int bb = 0; bb < NB; ++bb)
                acc += comp1[r * NB + bb] * basis1[bb * (IC * HC) + i * HC + o];
            W1t[t] = acc;
        } else if (t < n1 + n2) {
            int t2 = t - n1;
            int r = t2 / (HC * NC);
            int rem = t2 - r * (HC * NC);
            int o = rem >> 4, i = rem & 15;
            float acc = 0.f;
#pragma unroll
            for (int bb = 0; bb < NB; ++bb)
                acc += comp2[r * NB + bb] * basis2[bb * (HC * NC) + i * NC + o];
            W2t[t2] = acc;
        } else if (t < n1 + n2 + n3) {
            int t3 = t - n1 - n2;
            int o = t3 >> 6, i = t3 & 63;
            r1t[t3] = root1[i * HC + o];
        } else if (t < n1 + n2 + n3 + n4) {
            int t4 = t - n1 - n2 - n3;
            int o = t4 >> 4, i = t4 & 15;
            r2t[t4] = root2[i * NC + o];
        }
    } else {
        int tid = threadIdx.x;
        for (int i = tid; i < NR; i += 256) lh[i] = 0;
        __syncthreads();
        int e = (b - WBLK) * 256 + tid;
        if (e < NE) {
            int r = et[e];
            atomicAdd(&cnt[dst[e] * NR + r], 1);
            atomicAdd(&lh[r], 1);
        }
        __syncthreads();
        for (int i = tid; i < NR; i += 256)
            if (lh[i]) atomicAdd(&hist[i], lh[i]);
    }
}

// ---------------- exclusive scan over 90 bins (binStart only; cursors live in zeroed region) ----------------
__global__ void k_scan(const int* __restrict__ hist, int* __restrict__ binStart) {
    if (blockIdx.x == 0 && threadIdx.x == 0) {
        int run = 0;
        for (int r = 0; r < NR; ++r) {
            binStart[r] = run;
            run += hist[r];
        }
        binStart[NR] = run;
    }
}

// ---------------- two-level scatter: LDS rank + one global atomic per (rel, block) ----------------
// cursor[] starts at 0 (memset region): pos = binStart[r] + cursor-offset + rank.
__global__ void __launch_bounds__(256)
k_scatter(const int* __restrict__ src, const int* __restrict__ dst,
          const int* __restrict__ et, const int* __restrict__ cnt,
          const int* __restrict__ binStart, int* __restrict__ cursor,
          int* __restrict__ sSrc, int* __restrict__ sDst,
          float* __restrict__ sNrm) {
    __shared__ int lhist[NR];
    __shared__ int lbase[NR];
    int tid = threadIdx.x;
    for (int i = tid; i < NR; i += blockDim.x) lhist[i] = 0;
    __syncthreads();
    int e = blockIdx.x * blockDim.x + tid;
    int r = 0, d = 0, s = 0, myrank = 0;
    bool active = (e < NE);
    if (active) {
        r = et[e];
        d = dst[e];
        s = src[e];
        myrank = atomicAdd(&lhist[r], 1);      // LDS atomic = in-block rank
    }
    __syncthreads();
    for (int i = tid; i < NR; i += blockDim.x) {
        int c = lhist[i];
        lbase[i] = c ? (binStart[i] + atomicAdd(&cursor[i], c)) : 0;
    }
    __syncthreads();
    if (active) {
        int pos = lbase[r] + myrank;
        if (pos < NE) {                        // clamp: protects rocprof kernel-replay (stale cursors)
            sSrc[pos] = s;
            sDst[pos] = d;
            int c = cnt[d * NR + r];
            sNrm[pos] = 1.0f / (float)(c > 1 ? c : 1);
        }
    }
}

// ---------------- layer-1 messages: 16 edges x 16 outs per block, W in padded LDS (round-9 proven) ----------------
__global__ void __launch_bounds__(256)
k_msg1(const int* __restrict__ binStart, const int* __restrict__ sSrc,
       const int* __restrict__ sDst, const float* __restrict__ sNrm,
       const float* __restrict__ x, const float* __restrict__ W1t,
       float* __restrict__ agg1) {
    int r = blockIdx.x;
    int base = binStart[r], end = binStart[r + 1];
    int chunk0 = base + (int)blockIdx.y * EPB1;
    if (chunk0 >= end) return;
    __shared__ float wsh[16 * 68];        // [o][68] pad: <=2-way bank aliasing (free)
    {
        int t = threadIdx.x;              // 256 float4 = full 16x64 tile
        float4 v = ((const float4*)(W1t + r * (IC * HC)))[t];
        int o = t >> 4, i4 = t & 15;
        float* dp = &wsh[o * 68 + 4 * i4];
        dp[0] = v.x; dp[1] = v.y; dp[2] = v.z; dp[3] = v.w;
    }
    __syncthreads();
    int el = threadIdx.x >> 4;            // local edge 0..15
    int o  = threadIdx.x & 15;            // output channel
    int pos = chunk0 + el;
    if (pos >= end) return;
    int s = sSrc[pos], d = sDst[pos];
    float nm = sNrm[pos];
    const float4* xr = (const float4*)(x + s * IC);
    float acc = 0.f;
#pragma unroll
    for (int iv = 0; iv < 16; ++iv) {
        float4 xv = xr[iv];                                   // broadcast across 16 lanes
        float4 w = *(const float4*)&wsh[o * 68 + 4 * iv];     // conflict-free
        acc += xv.x * w.x + xv.y * w.y + xv.z * w.z + xv.w * w.w;
    }
    atomicAdd(&agg1[d * HC + o], acc * nm);   // 16 consecutive lanes -> 1 cache line
}

// ---------------- layer-1 node update: h = relu(agg1 + x@root1 + bias1) ----------------
__global__ void k_node1(const float* __restrict__ x, const float* __restrict__ r1t,
                        const float* __restrict__ bias1, const float* __restrict__ agg1,
                        float* __restrict__ h) {
    int t = blockIdx.x * blockDim.x + threadIdx.x;
    if (t >= NN * HC) return;
    int n = t >> 4;
    int o = t & (HC - 1);
    const float4* xr = (const float4*)(x + n * IC);
    const float4* wr = (const float4*)(r1t + o * IC);
    float acc = agg1[t] + bias1[o];
#pragma unroll
    for (int iv = 0; iv < 16; ++iv) {
        float4 xv = xr[iv], w = wr[iv];
        acc += xv.x * w.x + xv.y * w.y + xv.z * w.z + xv.w * w.w;
    }
    h[t] = fmaxf(acc, 0.f);
}

// ---------------- layer-2 messages: 32 edges x 8 outs per block, W in padded LDS (round-9 proven) ----------------
__global__ void __launch_bounds__(256)
k_msg2(const int* __restrict__ binStart, const int* __restrict__ sSrc,
       const int* __restrict__ sDst, const float* __restrict__ sNrm,
       const float* __restrict__ h, const float* __restrict__ W2t,
       float* __restrict__ agg2) {
    int r = blockIdx.x;
    int base = binStart[r], end = binStart[r + 1];
    int chunk0 = base + (int)blockIdx.y * EPB2;
    if (chunk0 >= end) return;
    __shared__ float wsh[8 * 20];         // [o][20]: 8 disjoint 4-bank spans, conflict-free
    if (threadIdx.x < 32) {
        float4 v = ((const float4*)(W2t + r * (HC * NC)))[threadIdx.x];
        int o = threadIdx.x >> 2, i4 = threadIdx.x & 3;
        float* dp = &wsh[o * 20 + 4 * i4];
        dp[0] = v.x; dp[1] = v.y; dp[2] = v.z; dp[3] = v.w;
    }
    __syncthreads();
    int el = threadIdx.x >> 3;            // local edge 0..31
    int o  = threadIdx.x & 7;
    int pos = chunk0 + el;
    if (pos >= end) return;
    int s = sSrc[pos], d = sDst[pos];
    float nm = sNrm[pos];
    const float4* hr = (const float4*)(h + s * HC);
    float acc = 0.f;
#pragma unroll
    for (int iv = 0; iv < 4; ++iv) {
        float4 hv = hr[iv];                                   // broadcast across 8 lanes
        float4 w = *(const float4*)&wsh[o * 20 + 4 * iv];
        acc += hv.x * w.x + hv.y * w.y + hv.z * w.z + hv.w * w.w;
    }
    atomicAdd(&agg2[d * NC + o], acc * nm);   // 8 consecutive lanes -> 1 cache line
}

// ---------------- layer-2 node update + log_softmax ----------------
__global__ void k_node2(const float* __restrict__ h, const float* __restrict__ r2t,
                        const float* __restrict__ bias2, const float* __restrict__ agg2,
                        float* __restrict__ out) {
    int n = blockIdx.x * blockDim.x + threadIdx.x;
    if (n >= NN) return;
    const float4* hr = (const float4*)(h + n * HC);
    float4 hv[4];
#pragma unroll
    for (int iv = 0; iv < 4; ++iv) hv[iv] = hr[iv];
    float v[NC];
#pragma unroll
    for (int o = 0; o < NC; ++o) {
        const float4* wr = (const float4*)(r2t + o * HC);
        float acc = agg2[n * NC + o] + bias2[o];
#pragma unroll
        for (int iv = 0; iv < 4; ++iv) {
            float4 w = wr[iv];
            acc += hv[iv].x * w.x + hv[iv].y * w.y + hv[iv].z * w.z + hv[iv].w * w.w;
        }
        v[o] = acc;
    }
    float m = v[0];
#pragma unroll
    for (int o = 1; o < NC; ++o) m = fmaxf(m, v[o]);
    float s = 0.f;
#pragma unroll
    for (int o = 0; o < NC; ++o) s += expf(v[o] - m);
    float lse = m + logf(s);
    float4 o0, o1;
    o0.x = v[0] - lse; o0.y = v[1] - lse; o0.z = v[2] - lse; o0.w = v[3] - lse;
    o1.x = v[4] - lse; o1.y = v[5] - lse; o1.z = v[6] - lse; o1.w = v[7] - lse;
    float4* op = (float4*)(out + n * NC);
    op[0] = o0; op[1] = o1;
}

extern "C" void kernel_launch(void* const* d_in, const int* in_sizes, int n_in,
                              void* d_out, int out_size, void* d_ws, size_t ws_size,
                              hipStream_t stream) {
    const float* x      = (const float*)d_in[0];
    const int*   eidx   = (const int*)d_in[1];     // [2, NE]
    const int*   etype  = (const int*)d_in[2];
    const float* comp1  = (const float*)d_in[3];
    const float* basis1 = (const float*)d_in[4];
    const float* root1  = (const float*)d_in[5];
    const float* bias1  = (const float*)d_in[6];
    const float* comp2  = (const float*)d_in[7];
    const float* basis2 = (const float*)d_in[8];
    const float* root2  = (const float*)d_in[9];
    const float* bias2  = (const float*)d_in[10];
    float* out = (float*)d_out;

    const int* src = eidx;
    const int* dst = eidx + NE;

    char* ws = (char*)d_ws;
    size_t off = 0;
    auto alloc = [&](size_t bytes) {
        char* p = ws + off;
        off = (off + bytes + 255) & ~(size_t)255;
        return p;
    };
    // --- zero region (single memset): cnt | hist | cursor | agg1 | agg2 ---
    size_t zero0 = off;
    int*   cnt    = (int*)  alloc((size_t)NN * NR * sizeof(int));  // 14.4 MB
    int*   hist   = (int*)  alloc(NR * sizeof(int));
    int*   cursor = (int*)  alloc(NR * sizeof(int));
    float* agg1   = (float*)alloc(NN * HC * sizeof(float));        // 2.56 MB
    float* agg2   = (float*)alloc(NN * NC * sizeof(float));        // 1.28 MB
    size_t zeroBytes = off - zero0;
    // --- rest ---
    float* W1t  = (float*)alloc(NR * IC * HC * sizeof(float));     // 368640
    float* W2t  = (float*)alloc(NR * HC * NC * sizeof(float));     // 46080
    float* r1t  = (float*)alloc(IC * HC * sizeof(float));          // 4096
    float* r2t  = (float*)alloc(HC * NC * sizeof(float));          // 512
    int*   binStart = (int*)alloc((NR + 1) * sizeof(int));
    int*   sSrc = (int*)  alloc(NE * sizeof(int));                 // 1.6 MB
    int*   sDst = (int*)  alloc(NE * sizeof(int));                 // 1.6 MB
    float* sNrm = (float*)alloc(NE * sizeof(float));               // 1.6 MB
    float* h    = (float*)alloc(NN * HC * sizeof(float));          // 2.56 MB

    hipMemsetAsync(ws + zero0, 0, zeroBytes, stream);

    const int B = 256;
    int cBlocks = (NE + B - 1) / B;          // 1563
    k_wc     <<<WBLK + cBlocks, B, 0, stream>>>(comp1, basis1, comp2, basis2,
                                                root1, root2, W1t, W2t, r1t, r2t,
                                                dst, etype, cnt, hist);
    k_scan   <<<1, 64, 0, stream>>>(hist, binStart);
    k_scatter<<<cBlocks, B, 0, stream>>>(src, dst, etype, cnt, binStart, cursor,
                                         sSrc, sDst, sNrm);
    k_msg1   <<<dim3(NR, CH1), B, 0, stream>>>(binStart, sSrc, sDst, sNrm, x, W1t, agg1);
    k_node1  <<<(NN * HC + B - 1) / B, B, 0, stream>>>(x, r1t, bias1, agg1, h);
    k_msg2   <<<dim3(NR, CH2), B, 0, stream>>>(binStart, sSrc, sDst, sNrm, h, W2t, agg2);
    k_node2  <<<(NN + B - 1) / B, B, 0, stream>>>(h, r2t, bias2, agg2, out);
}